// Round 9
// baseline (333.408 us; speedup 1.0000x reference)
//
#include <hip/hip_runtime.h>
#include <cstdint>
#include <cstddef>

#define DM   1024
#define DI   2048
#define SEQ  2048
#define NB   4
#define NTOK (NB*SEQ)   // 8192
#define CCH  32          // scan chunks per sequence
#define LC   (SEQ/CCH)   // 64 timesteps per chunk
#define KS   8           // K-split for xp_gemm

typedef __attribute__((ext_vector_type(8))) short short8v;
typedef __attribute__((ext_vector_type(4))) float f32x4;
typedef unsigned short u16;
typedef unsigned int   u32;

__device__ __forceinline__ float silu_f(float x){ return x / (1.f + __expf(-x)); }

// cheap softplus: inline v_exp + v_log (log1pf is a slow libm path — r7 lesson)
__device__ __forceinline__ float softplus_f(float x){
  return (x > 20.f) ? x : __logf(1.f + __expf(x));
}

__device__ __forceinline__ u16 f2bf(float f){
  union { float f; u32 u; } c; c.f = f;
  u32 u = c.u + 0x7FFFu + ((c.u >> 16) & 1u);   // RNE
  return (u16)(u >> 16);
}
__device__ __forceinline__ float b2f(u16 b){
  union { u32 u; float f; } c; c.u = ((u32)b) << 16; return c.f;
}
__device__ __forceinline__ float lo2f(u32 v){ union { u32 u; float f; } c; c.u = v << 16; return c.f; }
__device__ __forceinline__ float hi2f(u32 v){ union { u32 u; float f; } c; c.u = v & 0xFFFF0000u; return c.f; }
__device__ __forceinline__ u32 pack2(float a, float b){ return (u32)f2bf(a) | ((u32)f2bf(b) << 16); }

__device__ __forceinline__ void gl16(const void* g, void* l){
  __builtin_amdgcn_global_load_lds((const __attribute__((address_space(1))) void*)g,
                                   (__attribute__((address_space(3))) void*)l, 16, 0, 0);
}

// ---------------- fp32 -> bf16 bulk convert --------------------------------
__global__ __launch_bounds__(256) void cvtk(const float4* __restrict__ in,
                                            u16* __restrict__ outp, int n4)
{
  int i = blockIdx.x * 256 + threadIdx.x;
  if (i < n4) {
    float4 v = in[i];
    *(uint2*)(outp + (size_t)i * 4) = make_uint2(pack2(v.x, v.y), pack2(v.z, v.w));
  }
}

// ---------------- fp32 [R][Cn] -> bf16 [Cn][R] transpose-convert -----------
__global__ __launch_bounds__(256) void transcvt(
    const float* __restrict__ W, u16* __restrict__ Wt, int R, int Cn)
{
  __shared__ float t[64][65];
  const int tid = threadIdx.x;
  const int bx = blockIdx.x, by = blockIdx.y;
  const int lr4 = tid >> 6;   // 0..3
  const int lc  = tid & 63;
  #pragma unroll
  for (int p = 0; p < 16; ++p) {
    int lr = p * 4 + lr4;
    t[lr][lc] = W[(size_t)(by * 64 + lr) * Cn + bx * 64 + lc];
  }
  __syncthreads();
  #pragma unroll
  for (int p = 0; p < 16; ++p) {
    int orr = p * 4 + lr4;
    Wt[(size_t)(bx * 64 + orr) * R + by * 64 + lc] = f2bf(t[lc][orr]);
  }
}

// ---------------- small-weight prep ----------------------------------------
__global__ __launch_bounds__(256) void prep_smallw(
    const float* __restrict__ W_x, const float* __restrict__ W_dt,
    const float* __restrict__ W_Bp, u16* __restrict__ Wxt, u16* __restrict__ Wbig)
{
  int i = blockIdx.x * 256 + threadIdx.x;
  if (i < 32 * DI) {
    int j = i >> 11, c = i & (DI - 1);
    Wxt[i] = f2bf(W_x[c * 32 + j]);
  }
  int i2 = i - 32 * DI;
  if (i2 >= 0 && i2 < 2 * DI * 32) {
    int n = i2 >> 5, k = i2 & 31;
    float v;
    if (n < DI) v = (k < 16) ? W_dt[k * DI + n] : 0.f;
    else        v = (k >= 16) ? W_Bp[(k - 16) * DI + (n - DI)] : 0.f;
    Wbig[i2] = f2bf(v);
  }
}

// ---------------- 256^2 8-wave phase-scheduled MFMA GEMM -------------------
// A [M][K] bf16, Bt [N][K] bf16. BM=BN=256, BK=64, 512 thr (2x4 waves),
// 2 K-tile LDS dbuf (128 KiB), counted vmcnt(2) once per K-tile, raw
// s_barrier (no implicit drain), XOR-swizzled LDS via pre-swizzled global
// source (rule #21: linear gl16 dest + swz source + swz read).
// Output bf16, col-split at `split` (block-aligned: bn%256==0, split%256==0).
__global__ __launch_bounds__(512, 1) void gemm256(
    const u16* __restrict__ A, const u16* __restrict__ Bt,
    u16* __restrict__ C0, u16* __restrict__ C1,
    int M, int N, int K, int split, int ldc)
{
  __shared__ __align__(16) u16 Ab[2][16384];   // 2 x 256x64 bf16 = 64 KiB
  __shared__ __align__(16) u16 Bb[2][16384];   // 64 KiB
  const int tid = threadIdx.x, lane = tid & 63, w = tid >> 6;
  const int wm = w >> 2, wn = w & 3;
  const int bm = blockIdx.y * 256, bn = blockIdx.x * 256;
  const int NT = K >> 6;

  // staging: wave w rows [w*16, w*16+16) of each 128-row half, 2 issues (q=0,1 -> +8 rows)
  const int srow = w * 16 + (lane >> 3);
  const int kc   = ((lane & 7) ^ (lane >> 3)) << 3;   // swizzled u16 col offset
  const u16* Ag = A  + (size_t)bm * K;
  const u16* Bg = Bt + (size_t)bn * K;

  // fragment read constants
  const int lq = lane >> 4, l15 = lane & 15, l7 = lane & 7;
  const int xorv0 = ((lq * 16) ^ (l7 << 4)) >> 1;        // ks=0, u16 units
  const int xorv1 = ((64 + lq * 16) ^ (l7 << 4)) >> 1;   // ks=1
  const int abase = wm * 8192 + l15 * 64;
  const int bbase = (wn >> 1) * 8192 + (wn & 1) * 4096 + l15 * 64;

  f32x4 acc[8][4] = {};

  auto stA = [&](int h, int buf, int k0) {
    const u16* g = Ag + (size_t)(h * 128 + srow) * K + k0 + kc;
    u16* l = &Ab[buf][h * 8192 + w * 1024];
    gl16(g, l);
    gl16(g + (size_t)8 * K, l + 512);
  };
  auto stB = [&](int h, int buf, int k0) {
    const u16* g = Bg + (size_t)(h * 128 + srow) * K + k0 + kc;
    u16* l = &Bb[buf][h * 8192 + w * 1024];
    gl16(g, l);
    gl16(g + (size_t)8 * K, l + 512);
  };

  // prologue: tile 0 -> buf 0 (8 gl16, stays in flight through p0's vmcnt)
  stA(0, 0, 0); stA(1, 0, 0); stB(0, 0, 0); stB(1, 0, 0);

  short8v afr[4], bfr[4];
  #pragma unroll 1
  for (int t = 0; t < NT; ++t) {
    const int cur = t & 1, nxt = cur ^ 1, k1 = (t + 1) << 6;
    const u16* Ac = Ab[cur];
    const u16* Bc = Bb[cur];

    // ---- phase 0: stage A-half0(t+1); wait tile t complete; m0-3 x ks0
    if (t + 1 < NT) { stA(0, nxt, k1); asm volatile("s_waitcnt vmcnt(2)" ::: "memory"); }
    else            {                  asm volatile("s_waitcnt vmcnt(0)" ::: "memory"); }
    __builtin_amdgcn_s_barrier(); __builtin_amdgcn_sched_barrier(0);
    #pragma unroll
    for (int i = 0; i < 4; ++i) afr[i] = *(const short8v*)&Ac[abase + i * 1024 + xorv0];
    #pragma unroll
    for (int j = 0; j < 4; ++j) bfr[j] = *(const short8v*)&Bc[bbase + j * 1024 + xorv0];
    __builtin_amdgcn_s_setprio(1);
    #pragma unroll
    for (int i = 0; i < 4; ++i)
      #pragma unroll
      for (int j = 0; j < 4; ++j)
        acc[i][j] = __builtin_amdgcn_mfma_f32_16x16x32_bf16(afr[i], bfr[j], acc[i][j], 0, 0, 0);
    __builtin_amdgcn_s_setprio(0);
    __builtin_amdgcn_s_barrier(); __builtin_amdgcn_sched_barrier(0);

    // ---- phase 1: stage A-half1(t+1); m4-7 x ks0
    if (t + 1 < NT) stA(1, nxt, k1);
    #pragma unroll
    for (int i = 0; i < 4; ++i) afr[i] = *(const short8v*)&Ac[abase + (i + 4) * 1024 + xorv0];
    __builtin_amdgcn_s_setprio(1);
    #pragma unroll
    for (int i = 0; i < 4; ++i)
      #pragma unroll
      for (int j = 0; j < 4; ++j)
        acc[i + 4][j] = __builtin_amdgcn_mfma_f32_16x16x32_bf16(afr[i], bfr[j], acc[i + 4][j], 0, 0, 0);
    __builtin_amdgcn_s_setprio(0);
    __builtin_amdgcn_s_barrier(); __builtin_amdgcn_sched_barrier(0);

    // ---- phase 2: stage B-half0(t+1); m0-3 x ks1
    if (t + 1 < NT) stB(0, nxt, k1);
    #pragma unroll
    for (int i = 0; i < 4; ++i) afr[i] = *(const short8v*)&Ac[abase + i * 1024 + xorv1];
    #pragma unroll
    for (int j = 0; j < 4; ++j) bfr[j] = *(const short8v*)&Bc[bbase + j * 1024 + xorv1];
    __builtin_amdgcn_s_setprio(1);
    #pragma unroll
    for (int i = 0; i < 4; ++i)
      #pragma unroll
      for (int j = 0; j < 4; ++j)
        acc[i][j] = __builtin_amdgcn_mfma_f32_16x16x32_bf16(afr[i], bfr[j], acc[i][j], 0, 0, 0);
    __builtin_amdgcn_s_setprio(0);
    __builtin_amdgcn_s_barrier(); __builtin_amdgcn_sched_barrier(0);

    // ---- phase 3: stage B-half1(t+1); m4-7 x ks1
    if (t + 1 < NT) stB(1, nxt, k1);
    #pragma unroll
    for (int i = 0; i < 4; ++i) afr[i] = *(const short8v*)&Ac[abase + (i + 4) * 1024 + xorv1];
    __builtin_amdgcn_s_setprio(1);
    #pragma unroll
    for (int i = 0; i < 4; ++i)
      #pragma unroll
      for (int j = 0; j < 4; ++j)
        acc[i + 4][j] = __builtin_amdgcn_mfma_f32_16x16x32_bf16(afr[i], bfr[j], acc[i + 4][j], 0, 0, 0);
    __builtin_amdgcn_s_setprio(0);
    __builtin_amdgcn_s_barrier(); __builtin_amdgcn_sched_barrier(0);
  }

  // epilogue: C row = (lane>>4)*4 + r, col = lane&15 (m89 mapping)
  const bool left = (bn < split);
  u16* Cp = left ? C0 : C1;
  const int cb = bn - (left ? 0 : split) + wn * 64 + l15;
  const int rb = bm + wm * 128 + lq * 4;
  #pragma unroll
  for (int i = 0; i < 8; ++i)
    #pragma unroll
    for (int j = 0; j < 4; ++j)
      #pragma unroll
      for (int r = 0; r < 4; ++r)
        Cp[(size_t)(rb + i * 16 + r) * ldc + cb + j * 16] = f2bf(acc[i][j][r]);
}

// ---------------- bf16 MFMA GEMM, m97 structure (kept for GEMM2) -----------
template<int OBF16>
__global__ __launch_bounds__(256) void gemm_bt(
    const u16* __restrict__ A, const u16* __restrict__ Bt,
    void* C0v, void* C1v, int M, int N, int K, int split, int ldc)
{
  __shared__ __align__(16) u16 Asm[128 * 32];
  __shared__ __align__(16) u16 Bsm[128 * 32];
  const int tid  = threadIdx.x;
  const int lane = tid & 63;
  const int w    = tid >> 6;
  const int wm   = w >> 1, wn = w & 1;
  const int bm = blockIdx.y * 128, bn = blockIdx.x * 128;

  f32x4 acc[4][4] = {};

  const int srow = w * 32 + (lane >> 2);
  const int soct = lane & 3;
  const u16* Ap = A  + (size_t)(bm + srow) * K + soct * 8;
  const u16* Bp = Bt + (size_t)(bn + srow) * K + soct * 8;
  u16* As0 = &Asm[w * 1024];
  u16* Bs0 = &Bsm[w * 1024];
  const size_t row16 = (size_t)16 * K;

  for (int k0 = 0; k0 < K; k0 += 32) {
    gl16(Ap + k0,         As0);
    gl16(Ap + k0 + row16, As0 + 512);
    gl16(Bp + k0,         Bs0);
    gl16(Bp + k0 + row16, Bs0 + 512);
    __syncthreads();
    short8v afr[4], bfr[4];
    #pragma unroll
    for (int i = 0; i < 4; ++i) {
      afr[i] = *(const short8v*)&Asm[(wm * 64 + i * 16 + (lane & 15)) * 32 + (lane >> 4) * 8];
      bfr[i] = *(const short8v*)&Bsm[(wn * 64 + i * 16 + (lane & 15)) * 32 + (lane >> 4) * 8];
    }
    #pragma unroll
    for (int i = 0; i < 4; ++i)
      #pragma unroll
      for (int j = 0; j < 4; ++j)
        acc[i][j] = __builtin_amdgcn_mfma_f32_16x16x32_bf16(afr[i], bfr[j], acc[i][j], 0, 0, 0);
    __syncthreads();
  }

  const bool left = (bn < split);
  const int cb = bn - (left ? 0 : split) + wn * 64 + (lane & 15);
  const int rb = bm + wm * 64 + (lane >> 4) * 4;
  if (OBF16) {
    u16* Cp = (u16*)(left ? C0v : C1v);
    #pragma unroll
    for (int i = 0; i < 4; ++i)
      #pragma unroll
      for (int j = 0; j < 4; ++j)
        #pragma unroll
        for (int r = 0; r < 4; ++r)
          Cp[(size_t)(rb + i * 16 + r) * ldc + cb + j * 16] = f2bf(acc[i][j][r]);
  } else {
    float* Cp = (float*)(left ? C0v : C1v);
    #pragma unroll
    for (int i = 0; i < 4; ++i)
      #pragma unroll
      for (int j = 0; j < 4; ++j)
        #pragma unroll
        for (int r = 0; r < 4; ++r)
          Cp[(size_t)(rb + i * 16 + r) * ldc + cb + j * 16] = acc[i][j][r];
  }
}

// ---------------- skinny GEMM: xp_part[gy] = u @ W_x (K-slice) -------------
__global__ __launch_bounds__(256) void xp_gemm(
    const u16* __restrict__ A, const u16* __restrict__ Bt, float* __restrict__ xpp)
{
  __shared__ __align__(16) u16 Asm[128 * 32];
  __shared__ __align__(16) u16 Bsm[32 * 32];
  const int tid = threadIdx.x, lane = tid & 63, w = tid >> 6;
  const int bm = blockIdx.x * 128;
  const int kbase = blockIdx.y * (DI / KS);
  f32x4 acc[2][2] = {};
  const int srow = w * 32 + (lane >> 2);
  const int soct = lane & 3;
  const u16* Ap = A + (size_t)(bm + srow) * DI + kbase + soct * 8;
  const u16* Bp = Bt + (size_t)(lane >> 2) * DI + kbase + soct * 8;
  u16* As0 = &Asm[w * 1024];

  for (int k0 = 0; k0 < DI / KS; k0 += 32) {
    gl16(Ap + k0,                      As0);
    gl16(Ap + k0 + (size_t)16 * DI,    As0 + 512);
    if (w == 0) {
      gl16(Bp + k0,                    Bsm);
      gl16(Bp + k0 + (size_t)16 * DI,  Bsm + 512);
    }
    __syncthreads();
    short8v af[2], bf[2];
    #pragma unroll
    for (int i = 0; i < 2; ++i)
      af[i] = *(const short8v*)&Asm[(w * 32 + i * 16 + (lane & 15)) * 32 + (lane >> 4) * 8];
    #pragma unroll
    for (int j = 0; j < 2; ++j)
      bf[j] = *(const short8v*)&Bsm[(j * 16 + (lane & 15)) * 32 + (lane >> 4) * 8];
    #pragma unroll
    for (int i = 0; i < 2; ++i)
      #pragma unroll
      for (int j = 0; j < 2; ++j)
        acc[i][j] = __builtin_amdgcn_mfma_f32_16x16x32_bf16(af[i], bf[j], acc[i][j], 0, 0, 0);
    __syncthreads();
  }
  float* op = xpp + (size_t)blockIdx.y * NTOK * 32;
  const int rb = bm + w * 32 + (lane >> 4) * 4;
  const int cb = lane & 15;
  #pragma unroll
  for (int i = 0; i < 2; ++i)
    #pragma unroll
    for (int j = 0; j < 2; ++j)
      #pragma unroll
      for (int r = 0; r < 4; ++r)
        op[(size_t)(rb + i * 16 + r) * 32 + cb + j * 16] = acc[i][j][r];
}

// ---------------- reduce KS partials -> xp bf16 ----------------------------
__global__ __launch_bounds__(256) void xp_reduce(
    const float* __restrict__ xpp, u16* __restrict__ xpb)
{
  int i = blockIdx.x * 256 + threadIdx.x;   // over NTOK*32
  float s = 0.f;
  #pragma unroll
  for (int k = 0; k < KS; ++k) s += xpp[(size_t)k * NTOK * 32 + i];
  xpb[i] = f2bf(s);
}

// ---------------- dt/ub GEMM: [xp][Wbig] K=32, fused epilogue --------------
__global__ __launch_bounds__(256) void dtub_gemm(
    const u16* __restrict__ A, const u16* __restrict__ Bt,
    const float* __restrict__ b_dt, const u16* __restrict__ u,
    u16* __restrict__ dt_out, u16* __restrict__ ub_out)
{
  __shared__ __align__(16) u16 Asm[128 * 32];
  __shared__ __align__(16) u16 Bsm[128 * 32];
  const int tid = threadIdx.x, lane = tid & 63, w = tid >> 6;
  const int wm = w >> 1, wn = w & 1;
  const int bm = blockIdx.y * 128, bn = blockIdx.x * 128;
  const int srow = w * 32 + (lane >> 2);
  const int soct = lane & 3;
  u16* As0 = &Asm[w * 1024];
  u16* Bs0 = &Bsm[w * 1024];
  gl16(A  + (size_t)(bm + srow) * 32 + soct * 8,       As0);
  gl16(A  + (size_t)(bm + srow) * 32 + soct * 8 + 512, As0 + 512);
  gl16(Bt + (size_t)(bn + srow) * 32 + soct * 8,       Bs0);
  gl16(Bt + (size_t)(bn + srow) * 32 + soct * 8 + 512, Bs0 + 512);
  __syncthreads();
  f32x4 acc[4][4] = {};
  short8v afr[4], bfr[4];
  #pragma unroll
  for (int i = 0; i < 4; ++i) {
    afr[i] = *(const short8v*)&Asm[(wm * 64 + i * 16 + (lane & 15)) * 32 + (lane >> 4) * 8];
    bfr[i] = *(const short8v*)&Bsm[(wn * 64 + i * 16 + (lane & 15)) * 32 + (lane >> 4) * 8];
  }
  #pragma unroll
  for (int i = 0; i < 4; ++i)
    #pragma unroll
    for (int j = 0; j < 4; ++j)
      acc[i][j] = __builtin_amdgcn_mfma_f32_16x16x32_bf16(afr[i], bfr[j], acc[i][j], 0, 0, 0);

  const int rb = bm + wm * 64 + (lane >> 4) * 4;
  const int cb = bn + wn * 64 + (lane & 15);
  if (bn < DI) {          // dt half
    float bd[4];
    #pragma unroll
    for (int j = 0; j < 4; ++j) bd[j] = b_dt[cb + j * 16];
    #pragma unroll
    for (int i = 0; i < 4; ++i)
      #pragma unroll
      for (int j = 0; j < 4; ++j)
        #pragma unroll
        for (int r = 0; r < 4; ++r) {
          float sp = softplus_f(acc[i][j][r] + bd[j]);
          sp = fminf(fmaxf(sp, 1e-4f), 1.0f);
          dt_out[(size_t)(rb + i * 16 + r) * DI + cb + j * 16] = f2bf(sp);
        }
  } else {                // ub half
    const int cn = cb - DI;
    #pragma unroll
    for (int i = 0; i < 4; ++i)
      #pragma unroll
      for (int j = 0; j < 4; ++j)
        #pragma unroll
        for (int r = 0; r < 4; ++r) {
          size_t off = (size_t)(rb + i * 16 + r) * DI + cn + j * 16;
          ub_out[off] = f2bf(b2f(u[off]) * acc[i][j][r]);
        }
  }
}

// ---------------- causal depthwise conv(4) + silu, bf16 io -----------------
__global__ __launch_bounds__(256) void conv_silu_k(
    const u16* __restrict__ xc, const float* __restrict__ cw, u16* __restrict__ u)
{
  int idx = blockIdx.x * 256 + threadIdx.x;   // over NTOK*DI/2
  int c = (idx & (DI / 2 - 1)) << 1;
  int r = idx >> 10;
  int t = r & (SEQ - 1);
  float4 w0 = ((const float4*)cw)[c];
  float4 w1 = ((const float4*)cw)[c + 1];
  const u16* base = xc + (size_t)r * DI + c;
  u32 v = *(const u32*)base;
  float a0 = w0.w * lo2f(v), a1 = w1.w * hi2f(v);
  if (t >= 1) { v = *(const u32*)(base - DI);     a0 += w0.z * lo2f(v); a1 += w1.z * hi2f(v); }
  if (t >= 2) { v = *(const u32*)(base - 2 * DI); a0 += w0.y * lo2f(v); a1 += w1.y * hi2f(v); }
  if (t >= 3) { v = *(const u32*)(base - 3 * DI); a0 += w0.x * lo2f(v); a1 += w1.x * hi2f(v); }
  *(u32*)(u + (size_t)r * DI + c) = pack2(silu_f(a0), silu_f(a1));
}

// ---------------- chunked parallel scan (bf16 in) --------------------------
__global__ __launch_bounds__(256) void scan_p1(
    const u16* __restrict__ dt_, const u16* __restrict__ ub,
    float* __restrict__ P, float* __restrict__ S)
{
  int idx = blockIdx.x * 256 + threadIdx.x;   // NB*CCH*DI/2
  int di = (idx & (DI / 2 - 1)) << 1;
  int bc = idx >> 10;
  int c  = bc & (CCH - 1);
  int b  = bc >> 5;
  size_t base = ((size_t)b * SEQ + (size_t)c * LC) * DI + di;
  float p0 = 1.f, s0 = 0.f, p1 = 1.f, s1 = 0.f;
  #pragma unroll 4
  for (int t = 0; t < LC; ++t) {
    size_t off = base + (size_t)t * DI;
    u32 dv = *(const u32*)(dt_ + off);
    u32 uv = *(const u32*)(ub + off);
    float a0 = 1.f - lo2f(dv), a1 = 1.f - hi2f(dv);
    s0 = s0 * a0 + lo2f(uv); p0 *= a0;
    s1 = s1 * a1 + hi2f(uv); p1 *= a1;
  }
  ((float2*)P)[idx] = make_float2(p0, p1);
  ((float2*)S)[idx] = make_float2(s0, s1);
}

__global__ __launch_bounds__(256) void scan_p2(
    const float* __restrict__ P, const float* __restrict__ S, float* __restrict__ Hin)
{
  int idx = blockIdx.x * 256 + threadIdx.x;   // NB*DI
  int di = idx & (DI - 1);
  int b  = idx >> 11;
  float h = 0.f;
  #pragma unroll
  for (int c = 0; c < CCH; ++c) {
    size_t off = ((size_t)b * CCH + c) * DI + di;
    Hin[off] = h;
    h = h * P[off] + S[off];
  }
}

// y bf16 in-place over dt (same-index read-before-write) — no __restrict__.
__global__ __launch_bounds__(256) void scan_p3(
    const u16* dt_, const u16* __restrict__ ub, const u16* __restrict__ u,
    const u16* __restrict__ z, const float* __restrict__ Dp_,
    const float* __restrict__ Hin, u16* y)
{
  int idx = blockIdx.x * 256 + threadIdx.x;   // NB*CCH*DI/2
  int di = (idx & (DI / 2 - 1)) << 1;
  int bc = idx >> 10;
  int c  = bc & (CCH - 1);
  int b  = bc >> 5;
  float2 dp = ((const float2*)Dp_)[di >> 1];
  float2 h2 = ((const float2*)Hin)[idx];
  float h0 = h2.x, h1 = h2.y;
  size_t base = ((size_t)b * SEQ + (size_t)c * LC) * DI + di;
  #pragma unroll 4
  for (int t = 0; t < LC; ++t) {
    size_t off = base + (size_t)t * DI;
    u32 dv = *(const u32*)(dt_ + off);
    u32 uv = *(const u32*)(ub + off);
    u32 uu = *(const u32*)(u + off);
    u32 zv = *(const u32*)(z + off);
    h0 = h0 * (1.f - lo2f(dv)) + lo2f(uv);
    h1 = h1 * (1.f - hi2f(dv)) + hi2f(uv);
    float y0 = (h0 + dp.x * lo2f(uu)) * silu_f(lo2f(zv));
    float y1 = (h1 + dp.y * hi2f(uu)) * silu_f(hi2f(zv));
    *(u32*)(y + off) = pack2(y0, y1);
  }
}

extern "C" void kernel_launch(void* const* d_in, const int* in_sizes, int n_in,
                              void* d_out, int out_size, void* d_ws, size_t ws_size,
                              hipStream_t stream)
{
  const float* x     = (const float*)d_in[0];
  const float* W_in  = (const float*)d_in[1];
  const float* cw    = (const float*)d_in[2];
  const float* W_x   = (const float*)d_in[3];
  const float* W_dt  = (const float*)d_in[4];
  const float* b_dt  = (const float*)d_in[5];
  const float* W_Bp  = (const float*)d_in[6];
  const float* Dp    = (const float*)d_in[7];
  const float* W_out = (const float*)d_in[8];
  float* out = (float*)d_out;

  const size_t SZ = (size_t)NTOK * DI;        // floats per ws region
  float* w    = (float*)d_ws;
  float* bufA = w;
  float* bufB = w + SZ;
  float* bufC = w + 2 * SZ;
  float* bufD = w + 3 * SZ;

  u16* xcb  = (u16*)bufA;                     // xc bf16 -> dt bf16 -> y bf16
  u16* zb   = (u16*)bufB;                     // z bf16 [NTOK][DI]
  u16* wtob = zb + (size_t)NTOK * DI;         // Wt_out bf16 [DM][DI]
  u16* wxt  = wtob + (size_t)DM * DI;         // Wxt bf16 [32][DI]
  u16* wbig = wxt + (size_t)32 * DI;          // Wbig bf16 [4096][32]
  u16* xbf  = (u16*)bufC;                     // x bf16 [NTOK][DM]
  u16* wtib = xbf + (size_t)NTOK * DM;        // Wt_in bf16 [2DI][DM]
  u16* ubf  = (u16*)bufC;                     // u bf16 (over dead xbf/wtib)
  u16* ubb  = (u16*)bufD;                     // ub bf16

  const size_t PS = (size_t)NB * CCH * DI;    // 262144 floats
  float* Pbuf   = out;                        // scan + xp scratch in d_out
  float* Sbuf   = out + PS;                   // (GEMM2 rewrites d_out fully)
  float* Hin    = out + 2 * PS;
  float* xppart = out + 3 * PS;               // [KS][NTOK][32] fp32 (8 MB)
  u16*   xpb    = (u16*)(out + 3 * PS + (size_t)KS * NTOK * 32);
  (void)ws_size; (void)in_sizes; (void)n_in; (void)out_size;

  // 0) one-shot conversions / weight prep
  cvtk<<<(NTOK * DM / 4) / 256, 256, 0, stream>>>((const float4*)x, xbf, NTOK * DM / 4);
  transcvt<<<dim3((2 * DI) / 64, DM / 64), 256, 0, stream>>>(W_in, wtib, DM, 2 * DI);
  transcvt<<<dim3(DM / 64, DI / 64), 256, 0, stream>>>(W_out, wtob, DI, DM);
  prep_smallw<<<(32 * DI + 2 * DI * 32) / 256, 256, 0, stream>>>(W_x, W_dt, W_Bp, wxt, wbig);

  // 1) xz = x @ W_in -> xc (bf16, bufA), z (bf16, bufB)   [256^2 phase-sched]
  gemm256<<<dim3((2 * DI) / 256, NTOK / 256), 512, 0, stream>>>(
      xbf, wtib, xcb, zb, NTOK, 2 * DI, DM, DI, DI);

  // 2) u = silu(causal depthwise conv(xc))
  conv_silu_k<<<(NTOK * DI / 2) / 256, 256, 0, stream>>>(xcb, cw, ubf);

  // 3) xp = u @ W_x (K-split MFMA + reduce), then dt/ub via K=32 MFMA
  xp_gemm<<<dim3(NTOK / 128, KS), 256, 0, stream>>>(ubf, wxt, xppart);
  xp_reduce<<<(NTOK * 32) / 256, 256, 0, stream>>>(xppart, xpb);
  dtub_gemm<<<dim3((2 * DI) / 128, NTOK / 128), 256, 0, stream>>>(
      xpb, wbig, b_dt, ubf, xcb, ubb);

  // 4) chunked scan + epilogue -> y bf16 (in place over dt)
  scan_p1<<<(NB * CCH * DI / 2) / 256, 256, 0, stream>>>(xcb, ubb, Pbuf, Sbuf);
  scan_p2<<<(NB * DI) / 256, 256, 0, stream>>>(Pbuf, Sbuf, Hin);
  scan_p3<<<(NB * CCH * DI / 2) / 256, 256, 0, stream>>>(xcb, ubb, ubf, zb, Dp, Hin, xcb);

  // 5) out = y @ W_out (fp32 out)
  gemm_bt<0><<<dim3(DM / 128, NTOK / 128), 256, 0, stream>>>(
      xcb, wtob, (void*)out, (void*)out, NTOK, DM, DI, DM, DM);
}

// Round 10
// 328.117 us; speedup vs baseline: 1.0161x; 1.0161x over previous
//
#include <hip/hip_runtime.h>
#include <cstdint>
#include <cstddef>

#define DM   1024
#define DI   2048
#define SEQ  2048
#define NB   4
#define NTOK (NB*SEQ)   // 8192
#define CCH  32          // scan chunks per sequence
#define LC   (SEQ/CCH)   // 64 timesteps per chunk
#define KS   8           // K-split for xp_gemm

typedef __attribute__((ext_vector_type(8))) short short8v;
typedef __attribute__((ext_vector_type(4))) float f32x4;
typedef unsigned short u16;
typedef unsigned int   u32;

__device__ __forceinline__ float silu_f(float x){ return x / (1.f + __expf(-x)); }

// cheap softplus: inline v_exp + v_log (log1pf is a slow libm path — r7 lesson)
__device__ __forceinline__ float softplus_f(float x){
  return (x > 20.f) ? x : __logf(1.f + __expf(x));
}

__device__ __forceinline__ u16 f2bf(float f){
  union { float f; u32 u; } c; c.f = f;
  u32 u = c.u + 0x7FFFu + ((c.u >> 16) & 1u);   // RNE
  return (u16)(u >> 16);
}
__device__ __forceinline__ float b2f(u16 b){
  union { u32 u; float f; } c; c.u = ((u32)b) << 16; return c.f;
}
__device__ __forceinline__ float lo2f(u32 v){ union { u32 u; float f; } c; c.u = v << 16; return c.f; }
__device__ __forceinline__ float hi2f(u32 v){ union { u32 u; float f; } c; c.u = v & 0xFFFF0000u; return c.f; }
__device__ __forceinline__ u32 pack2(float a, float b){ return (u32)f2bf(a) | ((u32)f2bf(b) << 16); }

__device__ __forceinline__ void gl16(const void* g, void* l){
  __builtin_amdgcn_global_load_lds((const __attribute__((address_space(1))) void*)g,
                                   (__attribute__((address_space(3))) void*)l, 16, 0, 0);
}

// ---------------- fp32 -> bf16 bulk convert --------------------------------
__global__ __launch_bounds__(256) void cvtk(const float4* __restrict__ in,
                                            u16* __restrict__ outp, int n4)
{
  int i = blockIdx.x * 256 + threadIdx.x;
  if (i < n4) {
    float4 v = in[i];
    *(uint2*)(outp + (size_t)i * 4) = make_uint2(pack2(v.x, v.y), pack2(v.z, v.w));
  }
}

// ---------------- fp32 [R][Cn] -> bf16 [Cn][R] transpose-convert -----------
__global__ __launch_bounds__(256) void transcvt(
    const float* __restrict__ W, u16* __restrict__ Wt, int R, int Cn)
{
  __shared__ float t[64][65];
  const int tid = threadIdx.x;
  const int bx = blockIdx.x, by = blockIdx.y;
  const int lr4 = tid >> 6;   // 0..3
  const int lc  = tid & 63;
  #pragma unroll
  for (int p = 0; p < 16; ++p) {
    int lr = p * 4 + lr4;
    t[lr][lc] = W[(size_t)(by * 64 + lr) * Cn + bx * 64 + lc];
  }
  __syncthreads();
  #pragma unroll
  for (int p = 0; p < 16; ++p) {
    int orr = p * 4 + lr4;
    Wt[(size_t)(bx * 64 + orr) * R + by * 64 + lc] = f2bf(t[lc][orr]);
  }
}

// ---------------- small-weight prep ----------------------------------------
__global__ __launch_bounds__(256) void prep_smallw(
    const float* __restrict__ W_x, const float* __restrict__ W_dt,
    const float* __restrict__ W_Bp, u16* __restrict__ Wxt, u16* __restrict__ Wbig)
{
  int i = blockIdx.x * 256 + threadIdx.x;
  if (i < 32 * DI) {
    int j = i >> 11, c = i & (DI - 1);
    Wxt[i] = f2bf(W_x[c * 32 + j]);
  }
  int i2 = i - 32 * DI;
  if (i2 >= 0 && i2 < 2 * DI * 32) {
    int n = i2 >> 5, k = i2 & 31;
    float v;
    if (n < DI) v = (k < 16) ? W_dt[k * DI + n] : 0.f;
    else        v = (k >= 16) ? W_Bp[(k - 16) * DI + (n - DI)] : 0.f;
    Wbig[i2] = f2bf(v);
  }
}

// ---------------- 3-deep pipelined MFMA GEMM -------------------------------
// A [M][K] bf16, Bt [N][K] bf16. BM=128, BN=256, BK=64, 512 thr (2m x 4n
// waves, 64x64/wave). 3 LDS tile-buffers (144 KiB); tile t issued 3 iters
// before use -> counted vmcnt(12) keeps 12 loads in flight (T4). One
// vmcnt+barrier pair per tile; no intra-tile barriers (compiler lgkmcnt).
// XOR swizzle via pre-swizzled GLOBAL source + swizzled ds_read (rule #21;
// r9-verified: bank conflicts = 0). Output: cols<split->C0 else C1.
template<int NT, int OBF16>
__global__ __launch_bounds__(512, 1) void gemm3p(
    const u16* __restrict__ A, const u16* __restrict__ Bt,
    void* C0v, void* C1v, int K, int split, int ldc)
{
  __shared__ __align__(16) u16 Ab[3][128 * 64];   // 3 x 16 KiB
  __shared__ __align__(16) u16 Bb[3][256 * 64];   // 3 x 32 KiB
  const int tid = threadIdx.x, lane = tid & 63, w = tid >> 6;
  const int wm = w >> 2, wn = w & 3;
  const int bm = blockIdx.y * 128, bn = blockIdx.x * 256;

  // staging geometry: per gl16-issue 512 thr x 16B = 64 rows x 128B.
  // thread -> row w*8 + (lane>>3), col-block lane&7, XOR-swizzled on the
  // GLOBAL side so LDS dest stays linear (base + lane*16).
  const int lr = lane >> 3;                       // row-in-8-group = row&7
  const int kc = ((lane & 7) ^ lr) << 3;          // swizzled col (u16)
  const u16* Ag = A  + (size_t)(bm + w * 8 + lr) * K + kc;
  const u16* Bg = Bt + (size_t)(bn + w * 8 + lr) * K + kc;

  // fragment-read constants (inverse swizzle on the LDS side)
  const int lq = lane >> 4, l15 = lane & 15;
  const int co0 = (( lq     ) ^ (l15 & 7)) << 3;  // ks=0 col (u16)
  const int co1 = ((lq + 4) ^ (l15 & 7)) << 3;    // ks=1
  const int abase = (wm * 64 + l15) * 64;
  const int bbase = (wn * 64 + l15) * 64;

  f32x4 acc[4][4] = {};

  auto issue = [&](int t, int buf) {
    const size_t k0 = (size_t)t << 6;
    #pragma unroll
    for (int q = 0; q < 2; ++q)
      gl16(Ag + (size_t)q * 64 * K + k0, &Ab[buf][q * 4096 + w * 512]);
    #pragma unroll
    for (int q = 0; q < 4; ++q)
      gl16(Bg + (size_t)q * 64 * K + k0, &Bb[buf][q * 4096 + w * 512]);
  };
  auto compute = [&](int buf) {
    const u16* Ac = Ab[buf];
    const u16* Bc = Bb[buf];
    short8v af[4], bf[4];
    #pragma unroll
    for (int ks = 0; ks < 2; ++ks) {
      const int co = ks ? co1 : co0;
      #pragma unroll
      for (int i = 0; i < 4; ++i) af[i] = *(const short8v*)&Ac[abase + i * 1024 + co];
      #pragma unroll
      for (int j = 0; j < 4; ++j) bf[j] = *(const short8v*)&Bc[bbase + j * 1024 + co];
      __builtin_amdgcn_s_setprio(1);
      #pragma unroll
      for (int i = 0; i < 4; ++i)
        #pragma unroll
        for (int j = 0; j < 4; ++j)
          acc[i][j] = __builtin_amdgcn_mfma_f32_16x16x32_bf16(af[i], bf[j], acc[i][j], 0, 0, 0);
      __builtin_amdgcn_s_setprio(0);
    }
  };

  // prologue: 3 tiles in flight (18 gl16/thread)
  issue(0, 0); issue(1, 1); issue(2, 2);
  int cur = 0;
  #pragma unroll 1
  for (int t = 0; t < NT - 2; ++t) {
    asm volatile("s_waitcnt vmcnt(12)" ::: "memory");   // tile t landed
    __builtin_amdgcn_s_barrier(); __builtin_amdgcn_sched_barrier(0);
    compute(cur);
    __builtin_amdgcn_s_barrier(); __builtin_amdgcn_sched_barrier(0);
    if (t + 3 < NT) issue(t + 3, cur);                  // reuse buf just read
    cur = (cur == 2) ? 0 : cur + 1;
  }
  asm volatile("s_waitcnt vmcnt(6)" ::: "memory");      // tile NT-2
  __builtin_amdgcn_s_barrier(); __builtin_amdgcn_sched_barrier(0);
  compute(cur);
  cur = (cur == 2) ? 0 : cur + 1;
  asm volatile("s_waitcnt vmcnt(0)" ::: "memory");      // tile NT-1
  __builtin_amdgcn_s_barrier(); __builtin_amdgcn_sched_barrier(0);
  compute(cur);

  // epilogue: C row = (lane>>4)*4 + r, col = lane&15 (m89 mapping)
  const bool left = (bn < split);
  const int cb = bn - (left ? 0 : split) + wn * 64 + l15;
  const int rb = bm + wm * 64 + lq * 4;
  if (OBF16) {
    u16* Cp = (u16*)(left ? C0v : C1v);
    #pragma unroll
    for (int i = 0; i < 4; ++i)
      #pragma unroll
      for (int j = 0; j < 4; ++j)
        #pragma unroll
        for (int r = 0; r < 4; ++r)
          Cp[(size_t)(rb + i * 16 + r) * ldc + cb + j * 16] = f2bf(acc[i][j][r]);
  } else {
    float* Cp = (float*)(left ? C0v : C1v);
    #pragma unroll
    for (int i = 0; i < 4; ++i)
      #pragma unroll
      for (int j = 0; j < 4; ++j)
        #pragma unroll
        for (int r = 0; r < 4; ++r)
          Cp[(size_t)(rb + i * 16 + r) * ldc + cb + j * 16] = acc[i][j][r];
  }
}

// ---------------- skinny GEMM: xp_part[gy] = u @ W_x (K-slice) -------------
__global__ __launch_bounds__(256) void xp_gemm(
    const u16* __restrict__ A, const u16* __restrict__ Bt, float* __restrict__ xpp)
{
  __shared__ __align__(16) u16 Asm[128 * 32];
  __shared__ __align__(16) u16 Bsm[32 * 32];
  const int tid = threadIdx.x, lane = tid & 63, w = tid >> 6;
  const int bm = blockIdx.x * 128;
  const int kbase = blockIdx.y * (DI / KS);
  f32x4 acc[2][2] = {};
  const int srow = w * 32 + (lane >> 2);
  const int soct = lane & 3;
  const u16* Ap = A + (size_t)(bm + srow) * DI + kbase + soct * 8;
  const u16* Bp = Bt + (size_t)(lane >> 2) * DI + kbase + soct * 8;
  u16* As0 = &Asm[w * 1024];

  for (int k0 = 0; k0 < DI / KS; k0 += 32) {
    gl16(Ap + k0,                      As0);
    gl16(Ap + k0 + (size_t)16 * DI,    As0 + 512);
    if (w == 0) {
      gl16(Bp + k0,                    Bsm);
      gl16(Bp + k0 + (size_t)16 * DI,  Bsm + 512);
    }
    __syncthreads();
    short8v af[2], bf[2];
    #pragma unroll
    for (int i = 0; i < 2; ++i)
      af[i] = *(const short8v*)&Asm[(w * 32 + i * 16 + (lane & 15)) * 32 + (lane >> 4) * 8];
    #pragma unroll
    for (int j = 0; j < 2; ++j)
      bf[j] = *(const short8v*)&Bsm[(j * 16 + (lane & 15)) * 32 + (lane >> 4) * 8];
    #pragma unroll
    for (int i = 0; i < 2; ++i)
      #pragma unroll
      for (int j = 0; j < 2; ++j)
        acc[i][j] = __builtin_amdgcn_mfma_f32_16x16x32_bf16(af[i], bf[j], acc[i][j], 0, 0, 0);
    __syncthreads();
  }
  float* op = xpp + (size_t)blockIdx.y * NTOK * 32;
  const int rb = bm + w * 32 + (lane >> 4) * 4;
  const int cb = lane & 15;
  #pragma unroll
  for (int i = 0; i < 2; ++i)
    #pragma unroll
    for (int j = 0; j < 2; ++j)
      #pragma unroll
      for (int r = 0; r < 4; ++r)
        op[(size_t)(rb + i * 16 + r) * 32 + cb + j * 16] = acc[i][j][r];
}

// ---------------- reduce KS partials -> xp bf16 ----------------------------
__global__ __launch_bounds__(256) void xp_reduce(
    const float* __restrict__ xpp, u16* __restrict__ xpb)
{
  int i = blockIdx.x * 256 + threadIdx.x;   // over NTOK*32
  float s = 0.f;
  #pragma unroll
  for (int k = 0; k < KS; ++k) s += xpp[(size_t)k * NTOK * 32 + i];
  xpb[i] = f2bf(s);
}

// ---------------- dt/ub GEMM: [xp][Wbig] K=32, fused epilogue --------------
__global__ __launch_bounds__(256) void dtub_gemm(
    const u16* __restrict__ A, const u16* __restrict__ Bt,
    const float* __restrict__ b_dt, const u16* __restrict__ u,
    u16* __restrict__ dt_out, u16* __restrict__ ub_out)
{
  __shared__ __align__(16) u16 Asm[128 * 32];
  __shared__ __align__(16) u16 Bsm[128 * 32];
  const int tid = threadIdx.x, lane = tid & 63, w = tid >> 6;
  const int wm = w >> 1, wn = w & 1;
  const int bm = blockIdx.y * 128, bn = blockIdx.x * 128;
  const int srow = w * 32 + (lane >> 2);
  const int soct = lane & 3;
  u16* As0 = &Asm[w * 1024];
  u16* Bs0 = &Bsm[w * 1024];
  gl16(A  + (size_t)(bm + srow) * 32 + soct * 8,       As0);
  gl16(A  + (size_t)(bm + srow) * 32 + soct * 8 + 512, As0 + 512);
  gl16(Bt + (size_t)(bn + srow) * 32 + soct * 8,       Bs0);
  gl16(Bt + (size_t)(bn + srow) * 32 + soct * 8 + 512, Bs0 + 512);
  __syncthreads();
  f32x4 acc[4][4] = {};
  short8v afr[4], bfr[4];
  #pragma unroll
  for (int i = 0; i < 4; ++i) {
    afr[i] = *(const short8v*)&Asm[(wm * 64 + i * 16 + (lane & 15)) * 32 + (lane >> 4) * 8];
    bfr[i] = *(const short8v*)&Bsm[(wn * 64 + i * 16 + (lane & 15)) * 32 + (lane >> 4) * 8];
  }
  #pragma unroll
  for (int i = 0; i < 4; ++i)
    #pragma unroll
    for (int j = 0; j < 4; ++j)
      acc[i][j] = __builtin_amdgcn_mfma_f32_16x16x32_bf16(afr[i], bfr[j], acc[i][j], 0, 0, 0);

  const int rb = bm + wm * 64 + (lane >> 4) * 4;
  const int cb = bn + wn * 64 + (lane & 15);
  if (bn < DI) {          // dt half
    float bd[4];
    #pragma unroll
    for (int j = 0; j < 4; ++j) bd[j] = b_dt[cb + j * 16];
    #pragma unroll
    for (int i = 0; i < 4; ++i)
      #pragma unroll
      for (int j = 0; j < 4; ++j)
        #pragma unroll
        for (int r = 0; r < 4; ++r) {
          float sp = softplus_f(acc[i][j][r] + bd[j]);
          sp = fminf(fmaxf(sp, 1e-4f), 1.0f);
          dt_out[(size_t)(rb + i * 16 + r) * DI + cb + j * 16] = f2bf(sp);
        }
  } else {                // ub half
    const int cn = cb - DI;
    #pragma unroll
    for (int i = 0; i < 4; ++i)
      #pragma unroll
      for (int j = 0; j < 4; ++j)
        #pragma unroll
        for (int r = 0; r < 4; ++r) {
          size_t off = (size_t)(rb + i * 16 + r) * DI + cn + j * 16;
          ub_out[off] = f2bf(b2f(u[off]) * acc[i][j][r]);
        }
  }
}

// ---------------- causal depthwise conv(4) + silu, bf16 io -----------------
__global__ __launch_bounds__(256) void conv_silu_k(
    const u16* __restrict__ xc, const float* __restrict__ cw, u16* __restrict__ u)
{
  int idx = blockIdx.x * 256 + threadIdx.x;   // over NTOK*DI/2
  int c = (idx & (DI / 2 - 1)) << 1;
  int r = idx >> 10;
  int t = r & (SEQ - 1);
  float4 w0 = ((const float4*)cw)[c];
  float4 w1 = ((const float4*)cw)[c + 1];
  const u16* base = xc + (size_t)r * DI + c;
  u32 v = *(const u32*)base;
  float a0 = w0.w * lo2f(v), a1 = w1.w * hi2f(v);
  if (t >= 1) { v = *(const u32*)(base - DI);     a0 += w0.z * lo2f(v); a1 += w1.z * hi2f(v); }
  if (t >= 2) { v = *(const u32*)(base - 2 * DI); a0 += w0.y * lo2f(v); a1 += w1.y * hi2f(v); }
  if (t >= 3) { v = *(const u32*)(base - 3 * DI); a0 += w0.x * lo2f(v); a1 += w1.x * hi2f(v); }
  *(u32*)(u + (size_t)r * DI + c) = pack2(silu_f(a0), silu_f(a1));
}

// ---------------- chunked parallel scan (bf16 in) --------------------------
__global__ __launch_bounds__(256) void scan_p1(
    const u16* __restrict__ dt_, const u16* __restrict__ ub,
    float* __restrict__ P, float* __restrict__ S)
{
  int idx = blockIdx.x * 256 + threadIdx.x;   // NB*CCH*DI/2
  int di = (idx & (DI / 2 - 1)) << 1;
  int bc = idx >> 10;
  int c  = bc & (CCH - 1);
  int b  = bc >> 5;
  size_t base = ((size_t)b * SEQ + (size_t)c * LC) * DI + di;
  float p0 = 1.f, s0 = 0.f, p1 = 1.f, s1 = 0.f;
  #pragma unroll 4
  for (int t = 0; t < LC; ++t) {
    size_t off = base + (size_t)t * DI;
    u32 dv = *(const u32*)(dt_ + off);
    u32 uv = *(const u32*)(ub + off);
    float a0 = 1.f - lo2f(dv), a1 = 1.f - hi2f(dv);
    s0 = s0 * a0 + lo2f(uv); p0 *= a0;
    s1 = s1 * a1 + hi2f(uv); p1 *= a1;
  }
  ((float2*)P)[idx] = make_float2(p0, p1);
  ((float2*)S)[idx] = make_float2(s0, s1);
}

__global__ __launch_bounds__(256) void scan_p2(
    const float* __restrict__ P, const float* __restrict__ S, float* __restrict__ Hin)
{
  int idx = blockIdx.x * 256 + threadIdx.x;   // NB*DI
  int di = idx & (DI - 1);
  int b  = idx >> 11;
  float h = 0.f;
  #pragma unroll
  for (int c = 0; c < CCH; ++c) {
    size_t off = ((size_t)b * CCH + c) * DI + di;
    Hin[off] = h;
    h = h * P[off] + S[off];
  }
}

// y bf16 in-place over dt (same-index read-before-write) — no __restrict__.
__global__ __launch_bounds__(256) void scan_p3(
    const u16* dt_, const u16* __restrict__ ub, const u16* __restrict__ u,
    const u16* __restrict__ z, const float* __restrict__ Dp_,
    const float* __restrict__ Hin, u16* y)
{
  int idx = blockIdx.x * 256 + threadIdx.x;   // NB*CCH*DI/2
  int di = (idx & (DI / 2 - 1)) << 1;
  int bc = idx >> 10;
  int c  = bc & (CCH - 1);
  int b  = bc >> 5;
  float2 dp = ((const float2*)Dp_)[di >> 1];
  float2 h2 = ((const float2*)Hin)[idx];
  float h0 = h2.x, h1 = h2.y;
  size_t base = ((size_t)b * SEQ + (size_t)c * LC) * DI + di;
  #pragma unroll 4
  for (int t = 0; t < LC; ++t) {
    size_t off = base + (size_t)t * DI;
    u32 dv = *(const u32*)(dt_ + off);
    u32 uv = *(const u32*)(ub + off);
    u32 uu = *(const u32*)(u + off);
    u32 zv = *(const u32*)(z + off);
    h0 = h0 * (1.f - lo2f(dv)) + lo2f(uv);
    h1 = h1 * (1.f - hi2f(dv)) + hi2f(uv);
    float y0 = (h0 + dp.x * lo2f(uu)) * silu_f(lo2f(zv));
    float y1 = (h1 + dp.y * hi2f(uu)) * silu_f(hi2f(zv));
    *(u32*)(y + off) = pack2(y0, y1);
  }
}

extern "C" void kernel_launch(void* const* d_in, const int* in_sizes, int n_in,
                              void* d_out, int out_size, void* d_ws, size_t ws_size,
                              hipStream_t stream)
{
  const float* x     = (const float*)d_in[0];
  const float* W_in  = (const float*)d_in[1];
  const float* cw    = (const float*)d_in[2];
  const float* W_x   = (const float*)d_in[3];
  const float* W_dt  = (const float*)d_in[4];
  const float* b_dt  = (const float*)d_in[5];
  const float* W_Bp  = (const float*)d_in[6];
  const float* Dp    = (const float*)d_in[7];
  const float* W_out = (const float*)d_in[8];
  float* out = (float*)d_out;

  const size_t SZ = (size_t)NTOK * DI;        // floats per ws region
  float* w    = (float*)d_ws;
  float* bufA = w;
  float* bufB = w + SZ;
  float* bufC = w + 2 * SZ;
  float* bufD = w + 3 * SZ;

  u16* xcb  = (u16*)bufA;                     // xc bf16 -> dt bf16 -> y bf16
  u16* zb   = (u16*)bufB;                     // z bf16 [NTOK][DI]
  u16* wtob = zb + (size_t)NTOK * DI;         // Wt_out bf16 [DM][DI]
  u16* wxt  = wtob + (size_t)DM * DI;         // Wxt bf16 [32][DI]
  u16* wbig = wxt + (size_t)32 * DI;          // Wbig bf16 [4096][32]
  u16* xbf  = (u16*)bufC;                     // x bf16 [NTOK][DM]
  u16* wtib = xbf + (size_t)NTOK * DM;        // Wt_in bf16 [2DI][DM]
  u16* ubf  = (u16*)bufC;                     // u bf16 (over dead xbf/wtib)
  u16* ubb  = (u16*)bufD;                     // ub bf16

  const size_t PS = (size_t)NB * CCH * DI;    // 262144 floats
  float* Pbuf   = out;                        // scan + xp scratch in d_out
  float* Sbuf   = out + PS;                   // (GEMM2 rewrites d_out fully)
  float* Hin    = out + 2 * PS;
  float* xppart = out + 3 * PS;               // [KS][NTOK][32] fp32 (8 MB)
  u16*   xpb    = (u16*)(out + 3 * PS + (size_t)KS * NTOK * 32);
  (void)ws_size; (void)in_sizes; (void)n_in; (void)out_size;

  // 0) one-shot conversions / weight prep
  cvtk<<<(NTOK * DM / 4) / 256, 256, 0, stream>>>((const float4*)x, xbf, NTOK * DM / 4);
  transcvt<<<dim3((2 * DI) / 64, DM / 64), 256, 0, stream>>>(W_in, wtib, DM, 2 * DI);
  transcvt<<<dim3(DM / 64, DI / 64), 256, 0, stream>>>(W_out, wtob, DI, DM);
  prep_smallw<<<(32 * DI + 2 * DI * 32) / 256, 256, 0, stream>>>(W_x, W_dt, W_Bp, wxt, wbig);

  // 1) xz = x @ W_in -> xc (bf16, bufA), z (bf16, bufB)   [3-deep pipeline]
  gemm3p<DM / 64, 1><<<dim3((2 * DI) / 256, NTOK / 128), 512, 0, stream>>>(
      xbf, wtib, (void*)xcb, (void*)zb, DM, DI, DI);

  // 2) u = silu(causal depthwise conv(xc))
  conv_silu_k<<<(NTOK * DI / 2) / 256, 256, 0, stream>>>(xcb, cw, ubf);

  // 3) xp = u @ W_x (K-split MFMA + reduce), then dt/ub via K=32 MFMA
  xp_gemm<<<dim3(NTOK / 128, KS), 256, 0, stream>>>(ubf, wxt, xppart);
  xp_reduce<<<(NTOK * 32) / 256, 256, 0, stream>>>(xppart, xpb);
  dtub_gemm<<<dim3((2 * DI) / 128, NTOK / 128), 256, 0, stream>>>(
      xpb, wbig, b_dt, ubf, xcb, ubb);

  // 4) chunked scan + epilogue -> y bf16 (in place over dt)
  scan_p1<<<(NB * CCH * DI / 2) / 256, 256, 0, stream>>>(xcb, ubb, Pbuf, Sbuf);
  scan_p2<<<(NB * DI) / 256, 256, 0, stream>>>(Pbuf, Sbuf, Hin);
  scan_p3<<<(NB * CCH * DI / 2) / 256, 256, 0, stream>>>(xcb, ubb, ubf, zb, Dp, Hin, xcb);

  // 5) out = y @ W_out (fp32 out)   [3-deep pipeline]
  gemm3p<DI / 64, 0><<<dim3(DM / 256, NTOK / 128), 512, 0, stream>>>(
      xcb, wtob, (void*)out, (void*)out, DI, DM, DM);
}

// Round 11
// 299.908 us; speedup vs baseline: 1.1117x; 1.0941x over previous
//
#include <hip/hip_runtime.h>
#include <cstdint>
#include <cstddef>

#define DM   1024
#define DI   2048
#define SEQ  2048
#define NB   4
#define NTOK (NB*SEQ)   // 8192
#define CCH  32          // scan chunks per sequence
#define LC   (SEQ/CCH)   // 64 timesteps per chunk
#define KS   8           // K-split for xp_gemm

typedef __attribute__((ext_vector_type(8))) short short8v;
typedef __attribute__((ext_vector_type(4))) float f32x4;
typedef unsigned short u16;
typedef unsigned int   u32;

__device__ __forceinline__ float silu_f(float x){ return x / (1.f + __expf(-x)); }

// cheap softplus: inline v_exp + v_log (log1pf is a slow libm path — r7 lesson)
__device__ __forceinline__ float softplus_f(float x){
  return (x > 20.f) ? x : __logf(1.f + __expf(x));
}

__device__ __forceinline__ u16 f2bf(float f){
  union { float f; u32 u; } c; c.f = f;
  u32 u = c.u + 0x7FFFu + ((c.u >> 16) & 1u);   // RNE
  return (u16)(u >> 16);
}
__device__ __forceinline__ float b2f(u16 b){
  union { u32 u; float f; } c; c.u = ((u32)b) << 16; return c.f;
}
__device__ __forceinline__ float lo2f(u32 v){ union { u32 u; float f; } c; c.u = v << 16; return c.f; }
__device__ __forceinline__ float hi2f(u32 v){ union { u32 u; float f; } c; c.u = v & 0xFFFF0000u; return c.f; }
__device__ __forceinline__ u32 pack2(float a, float b){ return (u32)f2bf(a) | ((u32)f2bf(b) << 16); }

__device__ __forceinline__ void gl16(const void* g, void* l){
  __builtin_amdgcn_global_load_lds((const __attribute__((address_space(1))) void*)g,
                                   (__attribute__((address_space(3))) void*)l, 16, 0, 0);
}

// ---------------- fp32 -> bf16 bulk convert --------------------------------
__global__ __launch_bounds__(256) void cvtk(const float4* __restrict__ in,
                                            u16* __restrict__ outp, int n4)
{
  int i = blockIdx.x * 256 + threadIdx.x;
  if (i < n4) {
    float4 v = in[i];
    *(uint2*)(outp + (size_t)i * 4) = make_uint2(pack2(v.x, v.y), pack2(v.z, v.w));
  }
}

// ---------------- fp32 [R][Cn] -> bf16 [Cn][R] transpose-convert -----------
__global__ __launch_bounds__(256) void transcvt(
    const float* __restrict__ W, u16* __restrict__ Wt, int R, int Cn)
{
  __shared__ float t[64][65];
  const int tid = threadIdx.x;
  const int bx = blockIdx.x, by = blockIdx.y;
  const int lr4 = tid >> 6;   // 0..3
  const int lc  = tid & 63;
  #pragma unroll
  for (int p = 0; p < 16; ++p) {
    int lr = p * 4 + lr4;
    t[lr][lc] = W[(size_t)(by * 64 + lr) * Cn + bx * 64 + lc];
  }
  __syncthreads();
  #pragma unroll
  for (int p = 0; p < 16; ++p) {
    int orr = p * 4 + lr4;
    Wt[(size_t)(bx * 64 + orr) * R + by * 64 + lc] = f2bf(t[lc][orr]);
  }
}

// ---------------- small-weight prep ----------------------------------------
__global__ __launch_bounds__(256) void prep_smallw(
    const float* __restrict__ W_x, const float* __restrict__ W_dt,
    const float* __restrict__ W_Bp, u16* __restrict__ Wxt, u16* __restrict__ Wbig)
{
  int i = blockIdx.x * 256 + threadIdx.x;
  if (i < 32 * DI) {
    int j = i >> 11, c = i & (DI - 1);
    Wxt[i] = f2bf(W_x[c * 32 + j]);
  }
  int i2 = i - 32 * DI;
  if (i2 >= 0 && i2 < 2 * DI * 32) {
    int n = i2 >> 5, k = i2 & 31;
    float v;
    if (n < DI) v = (k < 16) ? W_dt[k * DI + n] : 0.f;
    else        v = (k >= 16) ? W_Bp[(k - 16) * DI + (n - DI)] : 0.f;
    Wbig[i2] = f2bf(v);
  }
}

// ---------------- 2-resident-block pipelined MFMA GEMM ---------------------
// A [M][K] bf16, Bt [N][K] bf16. BM=BN=128, BK=64, 256 thr (2x2 waves,
// 64x64/wave). 2-deep LDS dbuf = 64 KiB -> 2 BLOCKS resident per CU
// (cross-block TLP hides vmcnt/barrier stalls — the r8-r10 1-resident
// designs lacked this and all plateaued at ~660 TF). Counted vmcnt(8):
// tile t+2 issued after compute(t), never drained mid-loop (T4). XOR
// swizzle via pre-swizzled GLOBAL source + swizzled ds_read (rule #21,
// r9-verified conflicts=0). Output: cols<split->C0 else C1.
template<int NT, int OBF16>
__global__ __launch_bounds__(256, 2) void gemm2b(
    const u16* __restrict__ A, const u16* __restrict__ Bt,
    void* C0v, void* C1v, int K, int split, int ldc)
{
  __shared__ __align__(16) u16 Ab[2][128 * 64];   // 2 x 16 KiB
  __shared__ __align__(16) u16 Bb[2][128 * 64];   // 2 x 16 KiB
  const int tid = threadIdx.x, lane = tid & 63, w = tid >> 6;
  const int wm = w >> 1, wn = w & 1;
  const int bm = blockIdx.y * 128, bn = blockIdx.x * 128;

  // staging: per gl16-issue 256 thr x 16B = 32 rows x 128B; 4 issues per
  // operand tile. thread -> row q*32 + (tid>>3), colblock tid&7, XOR-
  // swizzled on the GLOBAL side so the LDS dest stays linear.
  const int srow8 = tid >> 3;                     // 0..31
  const int kc = ((tid & 7) ^ (srow8 & 7)) << 3;  // swizzled u16 col
  const u16* Ag = A  + (size_t)(bm + srow8) * K + kc;
  const u16* Bg = Bt + (size_t)(bn + srow8) * K + kc;

  // fragment-read constants (inverse swizzle on LDS side)
  const int lq = lane >> 4, l15 = lane & 15;
  const int co0 = ((lq    ) ^ (l15 & 7)) << 3;    // ks=0 col (u16)
  const int co1 = ((lq + 4) ^ (l15 & 7)) << 3;    // ks=1
  const int abase = (wm * 64 + l15) * 64;
  const int bbase = (wn * 64 + l15) * 64;

  f32x4 acc[4][4] = {};

  auto issue = [&](int t, int buf) {
    const size_t k0 = (size_t)t << 6;
    #pragma unroll
    for (int q = 0; q < 4; ++q)
      gl16(Ag + (size_t)(q * 32) * K + k0, &Ab[buf][q * 2048 + tid * 8]);
    #pragma unroll
    for (int q = 0; q < 4; ++q)
      gl16(Bg + (size_t)(q * 32) * K + k0, &Bb[buf][q * 2048 + tid * 8]);
  };
  auto compute = [&](int buf) {
    const u16* Ac = Ab[buf];
    const u16* Bc = Bb[buf];
    short8v af[4], bf[4];
    #pragma unroll
    for (int ks = 0; ks < 2; ++ks) {
      const int co = ks ? co1 : co0;
      #pragma unroll
      for (int i = 0; i < 4; ++i) af[i] = *(const short8v*)&Ac[abase + i * 1024 + co];
      #pragma unroll
      for (int j = 0; j < 4; ++j) bf[j] = *(const short8v*)&Bc[bbase + j * 1024 + co];
      __builtin_amdgcn_s_setprio(1);
      #pragma unroll
      for (int i = 0; i < 4; ++i)
        #pragma unroll
        for (int j = 0; j < 4; ++j)
          acc[i][j] = __builtin_amdgcn_mfma_f32_16x16x32_bf16(af[i], bf[j], acc[i][j], 0, 0, 0);
      __builtin_amdgcn_s_setprio(0);
    }
  };

  // prologue: 2 tiles in flight (16 gl16/thread)
  issue(0, 0); issue(1, 1);
  #pragma unroll 1
  for (int t = 0; t < NT; ++t) {
    if (t + 1 < NT) asm volatile("s_waitcnt vmcnt(8)" ::: "memory");  // tile t landed
    else            asm volatile("s_waitcnt vmcnt(0)" ::: "memory");
    __builtin_amdgcn_s_barrier(); __builtin_amdgcn_sched_barrier(0);
    compute(t & 1);
    __builtin_amdgcn_s_barrier(); __builtin_amdgcn_sched_barrier(0);
    if (t + 2 < NT) issue(t + 2, t & 1);            // reuse buf just read
  }

  // epilogue: C row = (lane>>4)*4 + r, col = lane&15 (m89 mapping)
  const bool left = (bn < split);
  const int cb = bn - (left ? 0 : split) + wn * 64 + l15;
  const int rb = bm + wm * 64 + lq * 4;
  if (OBF16) {
    u16* Cp = (u16*)(left ? C0v : C1v);
    #pragma unroll
    for (int i = 0; i < 4; ++i)
      #pragma unroll
      for (int j = 0; j < 4; ++j)
        #pragma unroll
        for (int r = 0; r < 4; ++r)
          Cp[(size_t)(rb + i * 16 + r) * ldc + cb + j * 16] = f2bf(acc[i][j][r]);
  } else {
    float* Cp = (float*)(left ? C0v : C1v);
    #pragma unroll
    for (int i = 0; i < 4; ++i)
      #pragma unroll
      for (int j = 0; j < 4; ++j)
        #pragma unroll
        for (int r = 0; r < 4; ++r)
          Cp[(size_t)(rb + i * 16 + r) * ldc + cb + j * 16] = acc[i][j][r];
  }
}

// ---------------- skinny GEMM: xp_part[gy] = u @ W_x (K-slice) -------------
__global__ __launch_bounds__(256) void xp_gemm(
    const u16* __restrict__ A, const u16* __restrict__ Bt, float* __restrict__ xpp)
{
  __shared__ __align__(16) u16 Asm[128 * 32];
  __shared__ __align__(16) u16 Bsm[32 * 32];
  const int tid = threadIdx.x, lane = tid & 63, w = tid >> 6;
  const int bm = blockIdx.x * 128;
  const int kbase = blockIdx.y * (DI / KS);
  f32x4 acc[2][2] = {};
  const int srow = w * 32 + (lane >> 2);
  const int soct = lane & 3;
  const u16* Ap = A + (size_t)(bm + srow) * DI + kbase + soct * 8;
  const u16* Bp = Bt + (size_t)(lane >> 2) * DI + kbase + soct * 8;
  u16* As0 = &Asm[w * 1024];

  for (int k0 = 0; k0 < DI / KS; k0 += 32) {
    gl16(Ap + k0,                      As0);
    gl16(Ap + k0 + (size_t)16 * DI,    As0 + 512);
    if (w == 0) {
      gl16(Bp + k0,                    Bsm);
      gl16(Bp + k0 + (size_t)16 * DI,  Bsm + 512);
    }
    __syncthreads();
    short8v af[2], bf[2];
    #pragma unroll
    for (int i = 0; i < 2; ++i)
      af[i] = *(const short8v*)&Asm[(w * 32 + i * 16 + (lane & 15)) * 32 + (lane >> 4) * 8];
    #pragma unroll
    for (int j = 0; j < 2; ++j)
      bf[j] = *(const short8v*)&Bsm[(j * 16 + (lane & 15)) * 32 + (lane >> 4) * 8];
    #pragma unroll
    for (int i = 0; i < 2; ++i)
      #pragma unroll
      for (int j = 0; j < 2; ++j)
        acc[i][j] = __builtin_amdgcn_mfma_f32_16x16x32_bf16(af[i], bf[j], acc[i][j], 0, 0, 0);
    __syncthreads();
  }
  float* op = xpp + (size_t)blockIdx.y * NTOK * 32;
  const int rb = bm + w * 32 + (lane >> 4) * 4;
  const int cb = lane & 15;
  #pragma unroll
  for (int i = 0; i < 2; ++i)
    #pragma unroll
    for (int j = 0; j < 2; ++j)
      #pragma unroll
      for (int r = 0; r < 4; ++r)
        op[(size_t)(rb + i * 16 + r) * 32 + cb + j * 16] = acc[i][j][r];
}

// ---------------- reduce KS partials -> xp bf16 ----------------------------
__global__ __launch_bounds__(256) void xp_reduce(
    const float* __restrict__ xpp, u16* __restrict__ xpb)
{
  int i = blockIdx.x * 256 + threadIdx.x;   // over NTOK*32
  float s = 0.f;
  #pragma unroll
  for (int k = 0; k < KS; ++k) s += xpp[(size_t)k * NTOK * 32 + i];
  xpb[i] = f2bf(s);
}

// ---------------- dt/ub GEMM: [xp][Wbig] K=32, fused epilogue --------------
__global__ __launch_bounds__(256) void dtub_gemm(
    const u16* __restrict__ A, const u16* __restrict__ Bt,
    const float* __restrict__ b_dt, const u16* __restrict__ u,
    u16* __restrict__ dt_out, u16* __restrict__ ub_out)
{
  __shared__ __align__(16) u16 Asm[128 * 32];
  __shared__ __align__(16) u16 Bsm[128 * 32];
  const int tid = threadIdx.x, lane = tid & 63, w = tid >> 6;
  const int wm = w >> 1, wn = w & 1;
  const int bm = blockIdx.y * 128, bn = blockIdx.x * 128;
  const int srow = w * 32 + (lane >> 2);
  const int soct = lane & 3;
  u16* As0 = &Asm[w * 1024];
  u16* Bs0 = &Bsm[w * 1024];
  gl16(A  + (size_t)(bm + srow) * 32 + soct * 8,       As0);
  gl16(A  + (size_t)(bm + srow) * 32 + soct * 8 + 512, As0 + 512);
  gl16(Bt + (size_t)(bn + srow) * 32 + soct * 8,       Bs0);
  gl16(Bt + (size_t)(bn + srow) * 32 + soct * 8 + 512, Bs0 + 512);
  __syncthreads();
  f32x4 acc[4][4] = {};
  short8v afr[4], bfr[4];
  #pragma unroll
  for (int i = 0; i < 4; ++i) {
    afr[i] = *(const short8v*)&Asm[(wm * 64 + i * 16 + (lane & 15)) * 32 + (lane >> 4) * 8];
    bfr[i] = *(const short8v*)&Bsm[(wn * 64 + i * 16 + (lane & 15)) * 32 + (lane >> 4) * 8];
  }
  #pragma unroll
  for (int i = 0; i < 4; ++i)
    #pragma unroll
    for (int j = 0; j < 4; ++j)
      acc[i][j] = __builtin_amdgcn_mfma_f32_16x16x32_bf16(afr[i], bfr[j], acc[i][j], 0, 0, 0);

  const int rb = bm + wm * 64 + (lane >> 4) * 4;
  const int cb = bn + wn * 64 + (lane & 15);
  if (bn < DI) {          // dt half
    float bd[4];
    #pragma unroll
    for (int j = 0; j < 4; ++j) bd[j] = b_dt[cb + j * 16];
    #pragma unroll
    for (int i = 0; i < 4; ++i)
      #pragma unroll
      for (int j = 0; j < 4; ++j)
        #pragma unroll
        for (int r = 0; r < 4; ++r) {
          float sp = softplus_f(acc[i][j][r] + bd[j]);
          sp = fminf(fmaxf(sp, 1e-4f), 1.0f);
          dt_out[(size_t)(rb + i * 16 + r) * DI + cb + j * 16] = f2bf(sp);
        }
  } else {                // ub half
    const int cn = cb - DI;
    #pragma unroll
    for (int i = 0; i < 4; ++i)
      #pragma unroll
      for (int j = 0; j < 4; ++j)
        #pragma unroll
        for (int r = 0; r < 4; ++r) {
          size_t off = (size_t)(rb + i * 16 + r) * DI + cn + j * 16;
          ub_out[off] = f2bf(b2f(u[off]) * acc[i][j][r]);
        }
  }
}

// ---------------- causal depthwise conv(4) + silu, bf16 io -----------------
__global__ __launch_bounds__(256) void conv_silu_k(
    const u16* __restrict__ xc, const float* __restrict__ cw, u16* __restrict__ u)
{
  int idx = blockIdx.x * 256 + threadIdx.x;   // over NTOK*DI/2
  int c = (idx & (DI / 2 - 1)) << 1;
  int r = idx >> 10;
  int t = r & (SEQ - 1);
  float4 w0 = ((const float4*)cw)[c];
  float4 w1 = ((const float4*)cw)[c + 1];
  const u16* base = xc + (size_t)r * DI + c;
  u32 v = *(const u32*)base;
  float a0 = w0.w * lo2f(v), a1 = w1.w * hi2f(v);
  if (t >= 1) { v = *(const u32*)(base - DI);     a0 += w0.z * lo2f(v); a1 += w1.z * hi2f(v); }
  if (t >= 2) { v = *(const u32*)(base - 2 * DI); a0 += w0.y * lo2f(v); a1 += w1.y * hi2f(v); }
  if (t >= 3) { v = *(const u32*)(base - 3 * DI); a0 += w0.x * lo2f(v); a1 += w1.x * hi2f(v); }
  *(u32*)(u + (size_t)r * DI + c) = pack2(silu_f(a0), silu_f(a1));
}

// ---------------- chunked parallel scan (bf16 in) --------------------------
__global__ __launch_bounds__(256) void scan_p1(
    const u16* __restrict__ dt_, const u16* __restrict__ ub,
    float* __restrict__ P, float* __restrict__ S)
{
  int idx = blockIdx.x * 256 + threadIdx.x;   // NB*CCH*DI/2
  int di = (idx & (DI / 2 - 1)) << 1;
  int bc = idx >> 10;
  int c  = bc & (CCH - 1);
  int b  = bc >> 5;
  size_t base = ((size_t)b * SEQ + (size_t)c * LC) * DI + di;
  float p0 = 1.f, s0 = 0.f, p1 = 1.f, s1 = 0.f;
  #pragma unroll 4
  for (int t = 0; t < LC; ++t) {
    size_t off = base + (size_t)t * DI;
    u32 dv = *(const u32*)(dt_ + off);
    u32 uv = *(const u32*)(ub + off);
    float a0 = 1.f - lo2f(dv), a1 = 1.f - hi2f(dv);
    s0 = s0 * a0 + lo2f(uv); p0 *= a0;
    s1 = s1 * a1 + hi2f(uv); p1 *= a1;
  }
  ((float2*)P)[idx] = make_float2(p0, p1);
  ((float2*)S)[idx] = make_float2(s0, s1);
}

__global__ __launch_bounds__(256) void scan_p2(
    const float* __restrict__ P, const float* __restrict__ S, float* __restrict__ Hin)
{
  int idx = blockIdx.x * 256 + threadIdx.x;   // NB*DI
  int di = idx & (DI - 1);
  int b  = idx >> 11;
  float h = 0.f;
  #pragma unroll
  for (int c = 0; c < CCH; ++c) {
    size_t off = ((size_t)b * CCH + c) * DI + di;
    Hin[off] = h;
    h = h * P[off] + S[off];
  }
}

// y bf16 in-place over dt (same-index read-before-write) — no __restrict__.
__global__ __launch_bounds__(256) void scan_p3(
    const u16* dt_, const u16* __restrict__ ub, const u16* __restrict__ u,
    const u16* __restrict__ z, const float* __restrict__ Dp_,
    const float* __restrict__ Hin, u16* y)
{
  int idx = blockIdx.x * 256 + threadIdx.x;   // NB*CCH*DI/2
  int di = (idx & (DI / 2 - 1)) << 1;
  int bc = idx >> 10;
  int c  = bc & (CCH - 1);
  int b  = bc >> 5;
  float2 dp = ((const float2*)Dp_)[di >> 1];
  float2 h2 = ((const float2*)Hin)[idx];
  float h0 = h2.x, h1 = h2.y;
  size_t base = ((size_t)b * SEQ + (size_t)c * LC) * DI + di;
  #pragma unroll 4
  for (int t = 0; t < LC; ++t) {
    size_t off = base + (size_t)t * DI;
    u32 dv = *(const u32*)(dt_ + off);
    u32 uv = *(const u32*)(ub + off);
    u32 uu = *(const u32*)(u + off);
    u32 zv = *(const u32*)(z + off);
    h0 = h0 * (1.f - lo2f(dv)) + lo2f(uv);
    h1 = h1 * (1.f - hi2f(dv)) + hi2f(uv);
    float y0 = (h0 + dp.x * lo2f(uu)) * silu_f(lo2f(zv));
    float y1 = (h1 + dp.y * hi2f(uu)) * silu_f(hi2f(zv));
    *(u32*)(y + off) = pack2(y0, y1);
  }
}

extern "C" void kernel_launch(void* const* d_in, const int* in_sizes, int n_in,
                              void* d_out, int out_size, void* d_ws, size_t ws_size,
                              hipStream_t stream)
{
  const float* x     = (const float*)d_in[0];
  const float* W_in  = (const float*)d_in[1];
  const float* cw    = (const float*)d_in[2];
  const float* W_x   = (const float*)d_in[3];
  const float* W_dt  = (const float*)d_in[4];
  const float* b_dt  = (const float*)d_in[5];
  const float* W_Bp  = (const float*)d_in[6];
  const float* Dp    = (const float*)d_in[7];
  const float* W_out = (const float*)d_in[8];
  float* out = (float*)d_out;

  const size_t SZ = (size_t)NTOK * DI;        // floats per ws region
  float* w    = (float*)d_ws;
  float* bufA = w;
  float* bufB = w + SZ;
  float* bufC = w + 2 * SZ;
  float* bufD = w + 3 * SZ;

  u16* xcb  = (u16*)bufA;                     // xc bf16 -> dt bf16 -> y bf16
  u16* zb   = (u16*)bufB;                     // z bf16 [NTOK][DI]
  u16* wtob = zb + (size_t)NTOK * DI;         // Wt_out bf16 [DM][DI]
  u16* wxt  = wtob + (size_t)DM * DI;         // Wxt bf16 [32][DI]
  u16* wbig = wxt + (size_t)32 * DI;          // Wbig bf16 [4096][32]
  u16* xbf  = (u16*)bufC;                     // x bf16 [NTOK][DM]
  u16* wtib = xbf + (size_t)NTOK * DM;        // Wt_in bf16 [2DI][DM]
  u16* ubf  = (u16*)bufC;                     // u bf16 (over dead xbf/wtib)
  u16* ubb  = (u16*)bufD;                     // ub bf16

  const size_t PS = (size_t)NB * CCH * DI;    // 262144 floats
  float* Pbuf   = out;                        // scan + xp scratch in d_out
  float* Sbuf   = out + PS;                   // (GEMM2 rewrites d_out fully)
  float* Hin    = out + 2 * PS;
  float* xppart = out + 3 * PS;               // [KS][NTOK][32] fp32 (8 MB)
  u16*   xpb    = (u16*)(out + 3 * PS + (size_t)KS * NTOK * 32);
  (void)ws_size; (void)in_sizes; (void)n_in; (void)out_size;

  // 0) one-shot conversions / weight prep
  cvtk<<<(NTOK * DM / 4) / 256, 256, 0, stream>>>((const float4*)x, xbf, NTOK * DM / 4);
  transcvt<<<dim3((2 * DI) / 64, DM / 64), 256, 0, stream>>>(W_in, wtib, DM, 2 * DI);
  transcvt<<<dim3(DM / 64, DI / 64), 256, 0, stream>>>(W_out, wtob, DI, DM);
  prep_smallw<<<(32 * DI + 2 * DI * 32) / 256, 256, 0, stream>>>(W_x, W_dt, W_Bp, wxt, wbig);

  // 1) xz = x @ W_in -> xc (bf16, bufA), z (bf16, bufB)  [2-resident pipeline]
  gemm2b<DM / 64, 1><<<dim3((2 * DI) / 128, NTOK / 128), 256, 0, stream>>>(
      xbf, wtib, (void*)xcb, (void*)zb, DM, DI, DI);

  // 2) u = silu(causal depthwise conv(xc))
  conv_silu_k<<<(NTOK * DI / 2) / 256, 256, 0, stream>>>(xcb, cw, ubf);

  // 3) xp = u @ W_x (K-split MFMA + reduce), then dt/ub via K=32 MFMA
  xp_gemm<<<dim3(NTOK / 128, KS), 256, 0, stream>>>(ubf, wxt, xppart);
  xp_reduce<<<(NTOK * 32) / 256, 256, 0, stream>>>(xppart, xpb);
  dtub_gemm<<<dim3((2 * DI) / 128, NTOK / 128), 256, 0, stream>>>(
      xpb, wbig, b_dt, ubf, xcb, ubb);

  // 4) chunked scan + epilogue -> y bf16 (in place over dt)
  scan_p1<<<(NB * CCH * DI / 2) / 256, 256, 0, stream>>>(xcb, ubb, Pbuf, Sbuf);
  scan_p2<<<(NB * DI) / 256, 256, 0, stream>>>(Pbuf, Sbuf, Hin);
  scan_p3<<<(NB * CCH * DI / 2) / 256, 256, 0, stream>>>(xcb, ubb, ubf, zb, Dp, Hin, xcb);

  // 5) out = y @ W_out (fp32 out)  [2-resident pipeline]
  gemm2b<DI / 64, 0><<<dim3(DM / 128, NTOK / 128), 256, 0, stream>>>(
      xcb, wtob, (void*)out, (void*)out, DI, DM, DM);
}